// Round 1
// baseline (334.813 us; speedup 1.0000x reference)
//
#include <hip/hip_runtime.h>
#include <hip/hip_bf16.h>
#include <math.h>

typedef int   v4i __attribute__((ext_vector_type(4)));
typedef float v4f __attribute__((ext_vector_type(4)));

#define B_DIM   256
#define IN_DIM  1024
#define H4      4096
#define NPLANE  4
#define WELEM   (NPLANE * IN_DIM * H4)   // 16777216 per weight tensor
#define XELEM   (B_DIM * IN_DIM)         // 262144

// ---- ws layout ----
// [0,16)        : maxes (w_ih, w_hh, b_ih, b_hh) as float bits (atomicMax on int)
// [64, +262144) : thresh double [2][4][4096]
// [+ , +1MB)    : X planes int8 [4][256][1024]  (values 0/1)
// [+ , +8MB)    : cmp bytes [2][4][256][4096]
#define WS_THRESH_OFF 64
#define WS_X_OFF      (64 + 262144)
#define WS_CMP_OFF    (64 + 262144 + 1048576)

// ---------------- Pass A1: global maxes ----------------
__global__ void k_max(const float* __restrict__ wih, const float* __restrict__ whh,
                      const float* __restrict__ bih, const float* __restrict__ bhh,
                      float* __restrict__ outm) {
  int b = blockIdx.x, t = threadIdx.x;
  const float* src; long n4; int slot; long bb, nb;
  if (b < 512)       { src = wih; n4 = WELEM / 4; slot = 0; bb = b;       nb = 512; }
  else if (b < 1024) { src = whh; n4 = WELEM / 4; slot = 1; bb = b - 512; nb = 512; }
  else if (b == 1024){ src = bih; n4 = 16384 / 4; slot = 2; bb = 0;       nb = 1;   }
  else               { src = bhh; n4 = 16384 / 4; slot = 3; bb = 0;       nb = 1;   }
  const v4f* p = (const v4f*)src;
  float m = -3.4e38f;
  for (long i = bb * 256 + t; i < n4; i += nb * 256) {
    v4f v = p[i];
    m = fmaxf(m, fmaxf(fmaxf(v.x, v.y), fmaxf(v.z, v.w)));
  }
#pragma unroll
  for (int off = 32; off >= 1; off >>= 1) m = fmaxf(m, __shfl_down(m, off, 64));
  __shared__ float sm[4];
  int w = t >> 6, ln = t & 63;
  if (ln == 0) sm[w] = m;
  __syncthreads();
  if (t == 0) {
    m = fmaxf(fmaxf(sm[0], sm[1]), fmaxf(sm[2], sm[3]));
    atomicMax((int*)&outm[slot], __float_as_int(m));  // maxes are > 0 for gaussian data
  }
}

// ---------------- Pass A2: input bit-planes + bias thresholds ----------------
__global__ void k_prep(const float* __restrict__ input,
                       const float* __restrict__ bih, const float* __restrict__ bhh,
                       const float* __restrict__ ebih, const float* __restrict__ ebhh,
                       const float* __restrict__ a1p, const float* __restrict__ maxm,
                       double* __restrict__ thresh, signed char* __restrict__ X) {
  int gid = blockIdx.x * 256 + threadIdx.x;
  if (blockIdx.x < 1024) {                       // X part: 262144 elements
    float a1 = a1p[0];
    float x = input[gid];
    // pact_a exactly as jax: sign(x)*0.5*(|x| - ||x|-a| + a)
    float t = fabsf(x), u = fabsf(t - a1);
    float sg = (x > 0.f) ? 0.5f : ((x < 0.f) ? -0.5f : 0.f);
    float p = sg * ((t - u) + a1);
    float inp01 = (p + a1) / (a1 * 2.0f);
    float q = rintf(15.0f * inp01);              // jnp.round is half-even, matches rintf
    int qi = (int)q;
#pragma unroll
    for (int pl = 0; pl < 4; ++pl)
      X[pl * XELEM + gid] = (signed char)((qi >> (3 - pl)) & 1);
  } else {                                       // thresh part: 32768 elements
    int i2 = gid - 262144;                       // s*16384 + n*4096 + col
    int s = i2 >> 14; int r = i2 & 16383;
    const float* bp = s ? bhh : bih;
    const float* ep = s ? ebhh : ebih;
    float mb = maxm[2 + s];
    float bv = bp[r], ev = ep[r];
    float xc = fminf(fmaxf(bv, -0.9921875f), 0.9921875f);
    float qv = rintf(xc * 128.f) * 0.0078125f;           // exact: k/128
    float noise = (ev * mb) * 0.1f;
    float beff = bv + ((qv - bv) + noise);               // jax op order
    thresh[i2] = 0.5 - (double)beff;                      // exact in f64
  }
}

// ---------------- Pass B: exact digit-GEMM ----------------
// grid: x = ntile (128 tiles of 32 cols), y = sp (s*4 + plane, 8)
// block: 512 threads = 8 waves; wave w covers output rows [w*32, w*32+32)
__global__ __launch_bounds__(512, 2) void k_gemm(
    const float* __restrict__ Wih, const float* __restrict__ Whh,
    const float* __restrict__ Eih, const float* __restrict__ Ehh,
    const float* __restrict__ maxm, const double* __restrict__ thresh,
    const signed char* __restrict__ X, unsigned char* __restrict__ cmp) {
  const int ntile = blockIdx.x;
  const int sp = blockIdx.y;
  const int s = sp >> 2, plane = sp & 3;
  const float* W = s ? Whh : Wih;
  const float* E = s ? Ehh : Eih;
  const float maxw = maxm[s];

  const int tid = threadIdx.x;
  const int wave = tid >> 6, lane = tid & 63, quad = lane >> 4, l15 = lane & 15;

  // digitized weights: [buf][digit][n(32)][k(64, pad to 80 for banks/alignment)]
  __shared__ __align__(16) signed char Blds[2][4][32][80];

  v4i acc[4][2][2];
#pragma unroll
  for (int d = 0; d < 4; ++d)
#pragma unroll
    for (int m = 0; m < 2; ++m)
#pragma unroll
      for (int n = 0; n < 2; ++n) acc[d][m][n] = (v4i){0, 0, 0, 0};

  const size_t wbase = (size_t)plane * IN_DIM * H4 + (size_t)ntile * 32;
  const int kl = tid >> 3;            // 0..63 (k row inside chunk)
  const int nc4 = (tid & 7) << 2;     // 0..28 (4 consecutive cols)

  const signed char* Xp = X + plane * XELEM;
  const int arow0 = wave * 32 + l15;

  // digitize one staged float4 pair and write LDS bytes
  auto convert_write = [&](v4f w4, v4f e4, int bf) {
#pragma unroll
    for (int e = 0; e < 4; ++e) {
      float w = w4[e], ev = e4[e];
      float xc = fminf(fmaxf(w, -0.9921875f), 0.9921875f);
      float qv = rintf(xc * 128.f) * 0.0078125f;
      float noise = (ev * maxw) * 0.1f;
      float a = w + ((qv - w) + noise);          // exact jax f32 chain -> w_eff
      // radix-128 digits, scale 8: a = (f0 + f1/128 + f2/128^2 + f3/128^3)/8 + O(2^-25)
      float x0 = a * 8.f;   float f0 = rintf(x0); float r0 = x0 - f0;
      float x1 = r0 * 128.f; float f1 = rintf(x1); float r1 = x1 - f1;
      float x2 = r1 * 128.f; float f2 = rintf(x2); float r2 = x2 - f2;
      float x3 = r2 * 128.f; float f3 = rintf(x3);
      int n = nc4 + e;
      Blds[bf][0][n][kl] = (signed char)(int)f0;
      Blds[bf][1][n][kl] = (signed char)(int)f1;
      Blds[bf][2][n][kl] = (signed char)(int)f2;
      Blds[bf][3][n][kl] = (signed char)(int)f3;
    }
  };

  // ---- prologue: stage chunk 0 into buf 0, load A frags for chunk 0 ----
  {
    const float* wp = W + wbase + (size_t)kl * H4 + nc4;
    const float* ep = E + wbase + (size_t)kl * H4 + nc4;
    v4f w4 = *(const v4f*)wp;
    v4f e4 = *(const v4f*)ep;
    convert_write(w4, e4, 0);
  }
  v4i afr[2];
  afr[0] = *(const v4i*)(Xp + (arow0) * IN_DIM + quad * 16);
  afr[1] = *(const v4i*)(Xp + (arow0 + 16) * IN_DIM + quad * 16);
  __syncthreads();

  for (int ch = 0; ch < 16; ++ch) {
    const int buf = ch & 1;
    // issue next-chunk global loads first (latency covered by MFMA below)
    v4f w4 = {0, 0, 0, 0}, e4 = {0, 0, 0, 0};
    v4i anx[2]; anx[0] = afr[0]; anx[1] = afr[1];
    if (ch < 15) {
      const float* wp = W + wbase + (size_t)((ch + 1) * 64 + kl) * H4 + nc4;
      const float* ep = E + wbase + (size_t)((ch + 1) * 64 + kl) * H4 + nc4;
      w4 = *(const v4f*)wp;
      e4 = *(const v4f*)ep;
      anx[0] = *(const v4i*)(Xp + (arow0) * IN_DIM + (ch + 1) * 64 + quad * 16);
      anx[1] = *(const v4i*)(Xp + (arow0 + 16) * IN_DIM + (ch + 1) * 64 + quad * 16);
    }
    // MFMA on current buffer
#pragma unroll
    for (int d = 0; d < 4; ++d) {
#pragma unroll
      for (int ns = 0; ns < 2; ++ns) {
        v4i bfr = *(const v4i*)&Blds[buf][d][ns * 16 + l15][quad * 16];
        acc[d][0][ns] = __builtin_amdgcn_mfma_i32_16x16x64_i8(afr[0], bfr, acc[d][0][ns], 0, 0, 0);
        acc[d][1][ns] = __builtin_amdgcn_mfma_i32_16x16x64_i8(afr[1], bfr, acc[d][1][ns], 0, 0, 0);
      }
    }
    if (ch < 15) convert_write(w4, e4, buf ^ 1);
    afr[0] = anx[0]; afr[1] = anx[1];
    __syncthreads();
  }

  // ---- epilogue: exact combine + compare ----
  const double inv = 1.0 / 16777216.0;   // /(8*128^3)
  const double* thp = thresh + (size_t)sp * H4;
  unsigned char* cp = cmp + (size_t)sp * B_DIM * H4;
#pragma unroll
  for (int ms = 0; ms < 2; ++ms) {
#pragma unroll
    for (int ns = 0; ns < 2; ++ns) {
      int col = ntile * 32 + ns * 16 + l15;
      double th = thp[col];
#pragma unroll
      for (int r = 0; r < 4; ++r) {
        long long T = ((long long)acc[0][ms][ns][r] << 21) + ((long long)acc[1][ms][ns][r] << 14)
                    + ((long long)acc[2][ms][ns][r] << 7)  +  (long long)acc[3][ms][ns][r];
        int row = wave * 32 + ms * 16 + quad * 4 + r;
        cp[(size_t)row * H4 + col] = ((double)T * inv > th) ? 1 : 0;
      }
    }
  }
}

// ---------------- Pass C: pointwise LSTM ----------------
__device__ __forceinline__ float pact_(float x, float a) {
  float t = fabsf(x), u = fabsf(t - a);
  float sg = (x > 0.f) ? 0.5f : ((x < 0.f) ? -0.5f : 0.f);
  return sg * ((t - u) + a);
}
__device__ __forceinline__ float quant_(float x, float a) {
  float xr = x / a;
  xr = fminf(fmaxf(xr, -0.9921875f), 0.9921875f);
  return rintf(xr * 128.f) * 0.0078125f * a;
}
__device__ __forceinline__ float sigm_(float x) { return 1.0f / (1.0f + expf(-x)); }

__global__ void k_pointwise(const unsigned char* __restrict__ cmp, const float* __restrict__ cx,
                            const float* a3, const float* a4, const float* a5, const float* a6,
                            const float* a7, const float* a8, const float* a9, const float* a10,
                            const float* a11, float* __restrict__ out) {
  int idx = blockIdx.x * 256 + threadIdx.x;   // 0..262143
  int b = idx >> 10, h = idx & 1023;
  float g[4];
#pragma unroll
  for (int gi = 0; gi < 4; ++gi) {
    int col = gi * 1024 + h;
    float acc = 0.f;
#pragma unroll
    for (int n = 0; n < 4; ++n) {
      int o = (int)cmp[((size_t)(0 * 4 + n) * B_DIM + b) * H4 + col]
            + (int)cmp[((size_t)(1 * 4 + n) * B_DIM + b) * H4 + col];
      float beta = (float)(8 >> n) / 15.0f;
      acc = acc + beta * (float)o;
    }
    g[gi] = acc;
  }
  float fg = quant_(pact_(sigm_(g[2]), a3[0]), a3[0]);
  float ig = quant_(pact_(sigm_(g[0]), a4[0]), a4[0]);
  float ac = quant_(pact_(tanhf(g[1]), a5[0]), a5[0]);
  float og = quant_(pact_(sigm_(g[3]), a6[0]), a6[0]);
  float cxv = cx[idx];
  float gc = quant_(pact_(cxv * fg, a7[0]), a7[0]);
  float ai = quant_(pact_(ig * ac, a8[0]), a8[0]);
  float nc = quant_(pact_(gc + ai, a9[0]), a9[0]);
  float acl = quant_(pact_(tanhf(nc), a10[0]), a10[0]);
  float nh = quant_(pact_(acl * og, a11[0]), a11[0]);
  out[idx] = nh;
  out[XELEM + idx] = nc;
}

extern "C" void kernel_launch(void* const* d_in, const int* in_sizes, int n_in,
                              void* d_out, int out_size, void* d_ws, size_t ws_size,
                              hipStream_t stream) {
  (void)in_sizes; (void)n_in; (void)out_size; (void)ws_size;
  const float* input = (const float*)d_in[0];
  const float* cx    = (const float*)d_in[2];
  const float* wih   = (const float*)d_in[3];
  const float* whh   = (const float*)d_in[4];
  const float* bih   = (const float*)d_in[5];
  const float* bhh   = (const float*)d_in[6];
  const float* ewih  = (const float*)d_in[7];
  const float* ewhh  = (const float*)d_in[8];
  const float* ebih  = (const float*)d_in[9];
  const float* ebhh  = (const float*)d_in[10];
  const float* a1    = (const float*)d_in[11];
  const float* a3    = (const float*)d_in[12];
  const float* a4    = (const float*)d_in[13];
  const float* a5    = (const float*)d_in[14];
  const float* a6    = (const float*)d_in[15];
  const float* a7    = (const float*)d_in[16];
  const float* a8    = (const float*)d_in[17];
  const float* a9    = (const float*)d_in[18];
  const float* a10   = (const float*)d_in[19];
  const float* a11   = (const float*)d_in[20];
  float* out = (float*)d_out;

  char* ws = (char*)d_ws;
  float*        maxm   = (float*)ws;
  double*       thresh = (double*)(ws + WS_THRESH_OFF);
  signed char*  X      = (signed char*)(ws + WS_X_OFF);
  unsigned char* cmp   = (unsigned char*)(ws + WS_CMP_OFF);

  hipMemsetAsync(ws, 0, 64, stream);
  k_max<<<1026, 256, 0, stream>>>(wih, whh, bih, bhh, maxm);
  k_prep<<<1152, 256, 0, stream>>>(input, bih, bhh, ebih, ebhh, a1, maxm, thresh, X);
  k_gemm<<<dim3(128, 8), 512, 0, stream>>>(wih, whh, ewih, ewhh, maxm, thresh, X, cmp);
  k_pointwise<<<1024, 256, 0, stream>>>(cmp, cx, a3, a4, a5, a6, a7, a8, a9, a10, a11, out);
}